// Round 1
// baseline (215.491 us; speedup 1.0000x reference)
//
#include <hip/hip_runtime.h>

// NeuralODE: y' = tanh(y@W1+b1)@W2+b2, fixed-step Dopri5, 48 static iters.
// Rows independent -> one persistent kernel, block = 32 rows, no inter-block comm.
// dt0 (Hairer heuristic on row 0) recomputed redundantly per block in fp32.
// Main integration: bf16 MFMA 16x16x32, weights as B-frags in registers,
// state/k_i in registers (C/D layout: col=lane&15, row=quad*4+reg).

typedef __attribute__((ext_vector_type(8))) short short8;  // 8 bf16 = 4 VGPRs
typedef __attribute__((ext_vector_type(4))) float f32x4;

#define LDSPAD 136  // 128 + 8 bf16 pad -> row stride 272B, 2-way-only bank aliasing

__device__ __forceinline__ short f2bf(float f) {
  union { float f; unsigned u; } v; v.f = f;
  unsigned r = v.u + 0x7FFFu + ((v.u >> 16) & 1u);  // RNE
  return (short)(r >> 16);
}

__device__ __forceinline__ float fast_tanh(float x) {
  // tanh(x) = 1 - 2/(e^{2x}+1); exact at +-inf, no branches. err ~1e-6.
  float e = __expf(2.0f * x);
  return 1.0f - __fdividef(2.0f, e + 1.0f);
}

__global__ __launch_bounds__(256, 1)
void node_kernel(const float* __restrict__ tptr, const float* __restrict__ x,
                 const float* __restrict__ W1, const float* __restrict__ b1,
                 const float* __restrict__ W2, const float* __restrict__ b2,
                 float* __restrict__ out) {
  const int tid  = threadIdx.x;
  const int lane = tid & 63;
  const int wave = tid >> 6;
  const int q    = lane >> 4;      // quad within wave
  const int colL = lane & 15;      // col within 16x16 tile (C layout) / m (A frag)
  const int rt     = wave & 1;         // row-tile (0..1) of the 32-row block tile
  const int ctBase = (wave >> 1) * 4;  // this wave owns col-tiles ctBase..ctBase+3
  const int blockRow = blockIdx.x * 32;

  __shared__ short AbufA[32][LDSPAD];  // staged A operand (y' as bf16)
  __shared__ short AbufB[32][LDSPAD];  // staged A operand (tanh hidden as bf16)
  __shared__ float sred[256];
  __shared__ float srowY[128], srowF[128], srowH[128], srowY2[128], srowF2[128], sscale[128];

  // ---------- block-wide sum (all 256 threads participate) ----------
  auto block_sum = [&](float v) -> float {
    sred[tid] = v;
    __syncthreads();
    if (tid < 64) {
      float s = sred[tid] + sred[tid + 64] + sred[tid + 128] + sred[tid + 192];
#pragma unroll
      for (int o = 32; o > 0; o >>= 1) s += __shfl_down(s, o, 64);
      if (tid == 0) sred[0] = s;
    }
    __syncthreads();
    float r = sred[0];
    __syncthreads();
    return r;
  };

  // ---------- single-row MLP in fp32 (for dt0), 128 threads active ----------
  auto mlp_row = [&](const float* yin, float* fout) {
    if (tid < 128) {
      float a = b1[tid];
      for (int j = 0; j < 128; ++j) a += yin[j] * W1[j * 128 + tid];
      srowH[tid] = fast_tanh(a);
    }
    __syncthreads();
    if (tid < 128) {
      float a = b2[tid];
      for (int j = 0; j < 128; ++j) a += srowH[j] * W2[j * 128 + tid];
      fout[tid] = a;
    }
    __syncthreads();
  };

  // ---------- dt0: faithful port of initial_step_size (row 0, fp32) ----------
  if (tid < 128) srowY[tid] = x[tid];
  __syncthreads();
  mlp_row(srowY, srowF);
  float t0 = 0.f, t1 = 0.f;
  if (tid < 128) {
    float sc = 1.4e-8f + fabsf(srowY[tid]) * 1.4e-8f;
    sscale[tid] = sc;
    float a = srowY[tid] / sc; t0 = a * a;
    float bq = srowF[tid] / sc; t1 = bq * bq;
  }
  float d0 = sqrtf(block_sum(t0));
  float d1 = sqrtf(block_sum(t1));
  float h0 = (d0 < 1e-5f || d1 < 1e-5f) ? 1e-6f : 0.01f * d0 / d1;
  if (tid < 128) srowY2[tid] = srowY[tid] + h0 * srowF[tid];
  __syncthreads();
  mlp_row(srowY2, srowF2);
  float t2 = 0.f;
  if (tid < 128) { float a = (srowF2[tid] - srowF[tid]) / sscale[tid]; t2 = a * a; }
  float d2 = sqrtf(block_sum(t2)) / h0;
  float h1 = (d1 <= 1e-15f && d2 <= 1e-15f) ? fmaxf(1e-6f, h0 * 1e-3f)
                                            : powf(0.01f / (d1 + d2), 0.2f);
  const float dt0v = fminf(100.f * h0, h1);

  // ---------- weight B-fragments (bf16) + biases into registers ----------
  // B-frag for 16x16x32: lane holds B[k = quad*8 + j][n = lane&15], j=0..7.
  short8 w1f[4][4], w2f[4][4];  // [col-tile][kIter]
  float b1c[4], b2c[4];
#pragma unroll
  for (int ci = 0; ci < 4; ++ci) {
    const int n = (ctBase + ci) * 16 + colL;
    b1c[ci] = b1[n];
    b2c[ci] = b2[n];
#pragma unroll
    for (int kt = 0; kt < 4; ++kt) {
      short8 v1, v2;
#pragma unroll
      for (int j = 0; j < 8; ++j) {
        const int k = kt * 32 + q * 8 + j;
        v1[j] = f2bf(W1[k * 128 + n]);
        v2[j] = f2bf(W2[k * 128 + n]);
      }
      w1f[ci][kt] = v1;
      w2f[ci][kt] = v2;
    }
  }

  // ---------- load state y (C-layout ownership: 16 elems/thread) ----------
  float yr[16];
#pragma unroll
  for (int e = 0; e < 16; ++e)
    yr[e] = x[(blockRow + rt * 16 + q * 4 + (e & 3)) * 128 + (ctBase + (e >> 2)) * 16 + colL];

  // ---------- helpers for one f-eval ----------
  auto stage = [&](const float* v) {  // write y' (bf16) into AbufA in A-layout
#pragma unroll
    for (int e = 0; e < 16; ++e)
      AbufA[rt * 16 + q * 4 + (e & 3)][(ctBase + (e >> 2)) * 16 + colL] = f2bf(v[e]);
    __syncthreads();
  };

  auto evalF = [&](float* kout) {
    f32x4 accH[4];
#pragma unroll
    for (int ci = 0; ci < 4; ++ci) accH[ci] = f32x4{b1c[ci], b1c[ci], b1c[ci], b1c[ci]};
#pragma unroll
    for (int kt = 0; kt < 4; ++kt) {
      short8 a = *(const short8*)&AbufA[rt * 16 + colL][kt * 32 + q * 8];
#pragma unroll
      for (int ci = 0; ci < 4; ++ci)
        accH[ci] = __builtin_amdgcn_mfma_f32_16x16x32_bf16(a, w1f[ci][kt], accH[ci], 0, 0, 0);
    }
#pragma unroll
    for (int e = 0; e < 16; ++e)
      AbufB[rt * 16 + q * 4 + (e & 3)][(ctBase + (e >> 2)) * 16 + colL] =
          f2bf(fast_tanh(accH[e >> 2][e & 3]));
    __syncthreads();
    f32x4 accF[4];
#pragma unroll
    for (int ci = 0; ci < 4; ++ci) accF[ci] = f32x4{b2c[ci], b2c[ci], b2c[ci], b2c[ci]};
#pragma unroll
    for (int kt = 0; kt < 4; ++kt) {
      short8 a = *(const short8*)&AbufB[rt * 16 + colL][kt * 32 + q * 8];
#pragma unroll
      for (int ci = 0; ci < 4; ++ci)
        accF[ci] = __builtin_amdgcn_mfma_f32_16x16x32_bf16(a, w2f[ci][kt], accF[ci], 0, 0, 0);
    }
#pragma unroll
    for (int e = 0; e < 16; ++e) kout[e] = accF[e >> 2][e & 3];
  };

  // ---------- main fixed-step Dopri5 loop ----------
  const float T = tptr[0] / 10.0f;  // t[0] / TIMESCALE
  float tt = 0.f;
  float k1[16], k2[16], k3[16], k4[16], k5[16], k6[16], yv[16];

#pragma unroll 1
  for (int it = 0; it < 48; ++it) {
    float dt = fminf(fmaxf(T - tt, 0.f), dt0v);
    if (dt > 0.f) {  // uniform across all threads and blocks
      stage(yr); evalF(k1);
#pragma unroll
      for (int e = 0; e < 16; ++e) yv[e] = yr[e] + dt * (0.2f * k1[e]);
      stage(yv); evalF(k2);
#pragma unroll
      for (int e = 0; e < 16; ++e) yv[e] = yr[e] + dt * (0.075f * k1[e] + 0.225f * k2[e]);
      stage(yv); evalF(k3);
#pragma unroll
      for (int e = 0; e < 16; ++e)
        yv[e] = yr[e] + dt * (0.9777777777777777f * k1[e] - 3.7333333333333334f * k2[e]
                            + 3.5555555555555554f * k3[e]);
      stage(yv); evalF(k4);
#pragma unroll
      for (int e = 0; e < 16; ++e)
        yv[e] = yr[e] + dt * (2.9525986892242035f * k1[e] - 11.595793324188385f * k2[e]
                            + 9.822892851699436f * k3[e] - 0.2908093278463649f * k4[e]);
      stage(yv); evalF(k5);
#pragma unroll
      for (int e = 0; e < 16; ++e)
        yv[e] = yr[e] + dt * (2.8462752525252526f * k1[e] - 10.757575757575758f * k2[e]
                            + 8.906422717743473f * k3[e] + 0.2784090909090909f * k4[e]
                            - 0.27351165254237287f * k5[e]);
      stage(yv); evalF(k6);
#pragma unroll
      for (int e = 0; e < 16; ++e)
        yr[e] += dt * (0.0911458333333333f * k1[e] + 0.449236298292902f * k3[e]
                     + 0.6510416666666666f * k4[e] - 0.32237617924528303f * k5[e]
                     + 0.13095238095238096f * k6[e]);
    }
    tt += dt;
  }

  // ---------- epilogue: out = stack([x, yT]) ----------
  {
    const float4* x4 = (const float4*)(x + blockRow * 128);
    float4* o4 = (float4*)(out + blockRow * 128);
#pragma unroll 1
    for (int i = tid; i < 1024; i += 256) o4[i] = x4[i];
    float* oy = out + 8192 * 128;
#pragma unroll
    for (int e = 0; e < 16; ++e)
      oy[(blockRow + rt * 16 + q * 4 + (e & 3)) * 128 + (ctBase + (e >> 2)) * 16 + colL] = yr[e];
  }
}

extern "C" void kernel_launch(void* const* d_in, const int* in_sizes, int n_in,
                              void* d_out, int out_size, void* d_ws, size_t ws_size,
                              hipStream_t stream) {
  const float* t  = (const float*)d_in[0];
  const float* x  = (const float*)d_in[1];
  const float* W1 = (const float*)d_in[2];
  const float* b1 = (const float*)d_in[3];
  const float* W2 = (const float*)d_in[4];
  const float* b2 = (const float*)d_in[5];
  float* out = (float*)d_out;
  node_kernel<<<dim3(256), dim3(256), 0, stream>>>(t, x, W1, b1, W2, b2, out);
}

// Round 2
// 172.069 us; speedup vs baseline: 1.2523x; 1.2523x over previous
//
#include <hip/hip_runtime.h>

// NeuralODE: y' = tanh(y@W1+b1)@W2+b2, fixed-step Dopri5, 48 static iters.
// Rows independent -> persistent kernel. R1: 512 blocks x 16 rows (2 blocks/CU,
// 2 waves/SIMD) for latency hiding; independent per-block barriers overlap.
// dt0 (Hairer heuristic on row 0) recomputed redundantly per block in fp32.
// Main integration: bf16 MFMA 16x16x32, weights as B-frags in registers,
// state/k_i in registers (C/D layout: col=lane&15, row=quad*4+reg).

typedef __attribute__((ext_vector_type(8))) short short8;  // 8 bf16 = 4 VGPRs
typedef __attribute__((ext_vector_type(4))) float f32x4;

#define LDSPAD 136  // 128 + 8 bf16 pad -> row stride 272B

__device__ __forceinline__ short f2bf(float f) {
  // round-half-up; bias negligible vs 0.1 error budget, ~half the VALU of RNE
  union { float f; unsigned u; } v; v.f = f;
  return (short)((v.u + 0x8000u) >> 16);
}

__device__ __forceinline__ float fast_tanh(float x) {
  // tanh(x) = 1 - 2/(e^{2x}+1); exact at +-inf, no branches.
  float e = __expf(2.0f * x);
  return 1.0f - __fdividef(2.0f, e + 1.0f);
}

__global__ __launch_bounds__(256, 2)
void node_kernel(const float* __restrict__ tptr, const float* __restrict__ x,
                 const float* __restrict__ W1, const float* __restrict__ b1,
                 const float* __restrict__ W2, const float* __restrict__ b2,
                 float* __restrict__ out) {
  const int tid  = threadIdx.x;
  const int lane = tid & 63;
  const int wave = tid >> 6;       // 0..3, each wave owns col-tiles wave*2, wave*2+1
  const int q    = lane >> 4;      // quad within wave
  const int colL = lane & 15;      // col within 16x16 tile (C layout) / m (A frag)
  const int ctBase = wave * 2;
  const int blockRow = blockIdx.x * 16;

  __shared__ short AbufA[16][LDSPAD];  // staged A operand (y' as bf16)
  __shared__ short AbufB[16][LDSPAD];  // staged A operand (tanh hidden as bf16)
  __shared__ float sred[256];
  __shared__ float srowY[128], srowF[128], srowH[128], srowY2[128], srowF2[128], sscale[128];

  // ---------- weight B-fragments (bf16) + biases into registers ----------
  // B-frag for 16x16x32: lane holds B[k = quad*8 + j][n = lane&15], j=0..7.
  short8 w1f[2][4], w2f[2][4];  // [col-tile][kIter]
  float b1c[2], b2c[2];
#pragma unroll
  for (int ci = 0; ci < 2; ++ci) {
    const int n = (ctBase + ci) * 16 + colL;
    b1c[ci] = b1[n];
    b2c[ci] = b2[n];
#pragma unroll
    for (int kt = 0; kt < 4; ++kt) {
      short8 v1, v2;
#pragma unroll
      for (int j = 0; j < 8; ++j) {
        const int k = kt * 32 + q * 8 + j;
        v1[j] = f2bf(W1[k * 128 + n]);
        v2[j] = f2bf(W2[k * 128 + n]);
      }
      w1f[ci][kt] = v1;
      w2f[ci][kt] = v2;
    }
  }

  // ---------- block-wide sum (all 256 threads participate) ----------
  auto block_sum = [&](float v) -> float {
    sred[tid] = v;
    __syncthreads();
    if (tid < 64) {
      float s = sred[tid] + sred[tid + 64] + sred[tid + 128] + sred[tid + 192];
#pragma unroll
      for (int o = 32; o > 0; o >>= 1) s += __shfl_down(s, o, 64);
      if (tid == 0) sred[0] = s;
    }
    __syncthreads();
    float r = sred[0];
    __syncthreads();
    return r;
  };

  // ---------- single-row MLP in fp32 (for dt0), 128 threads active ----------
  auto mlp_row = [&](const float* yin, float* fout) {
    if (tid < 128) {
      float a = b1[tid];
#pragma unroll 8
      for (int j = 0; j < 128; ++j) a += yin[j] * W1[j * 128 + tid];
      srowH[tid] = fast_tanh(a);
    }
    __syncthreads();
    if (tid < 128) {
      float a = b2[tid];
#pragma unroll 8
      for (int j = 0; j < 128; ++j) a += srowH[j] * W2[j * 128 + tid];
      fout[tid] = a;
    }
    __syncthreads();
  };

  // ---------- dt0: faithful port of initial_step_size (row 0, fp32) ----------
  if (tid < 128) srowY[tid] = x[tid];
  __syncthreads();
  mlp_row(srowY, srowF);
  float t0 = 0.f, t1 = 0.f;
  if (tid < 128) {
    float sc = 1.4e-8f + fabsf(srowY[tid]) * 1.4e-8f;
    sscale[tid] = sc;
    float a = srowY[tid] / sc; t0 = a * a;
    float bq = srowF[tid] / sc; t1 = bq * bq;
  }
  float d0 = sqrtf(block_sum(t0));
  float d1 = sqrtf(block_sum(t1));
  float h0 = (d0 < 1e-5f || d1 < 1e-5f) ? 1e-6f : 0.01f * d0 / d1;
  if (tid < 128) srowY2[tid] = srowY[tid] + h0 * srowF[tid];
  __syncthreads();
  mlp_row(srowY2, srowF2);
  float t2 = 0.f;
  if (tid < 128) { float a = (srowF2[tid] - srowF[tid]) / sscale[tid]; t2 = a * a; }
  float d2 = sqrtf(block_sum(t2)) / h0;
  float h1 = (d1 <= 1e-15f && d2 <= 1e-15f) ? fmaxf(1e-6f, h0 * 1e-3f)
                                            : powf(0.01f / (d1 + d2), 0.2f);
  const float dt0v = fminf(100.f * h0, h1);

  // ---------- load state y (C-layout ownership: 8 elems/thread) ----------
  float yr[8];
#pragma unroll
  for (int e = 0; e < 8; ++e)
    yr[e] = x[(blockRow + q * 4 + (e & 3)) * 128 + (ctBase + (e >> 2)) * 16 + colL];

  // ---------- helpers for one f-eval ----------
  auto stage = [&](const float* v) {  // write y' (bf16) into AbufA in A-layout
#pragma unroll
    for (int e = 0; e < 8; ++e)
      AbufA[q * 4 + (e & 3)][(ctBase + (e >> 2)) * 16 + colL] = f2bf(v[e]);
    __syncthreads();
  };

  auto evalF = [&](float* kout) {
    f32x4 accH[2];
#pragma unroll
    for (int ci = 0; ci < 2; ++ci) accH[ci] = f32x4{b1c[ci], b1c[ci], b1c[ci], b1c[ci]};
#pragma unroll
    for (int kt = 0; kt < 4; ++kt) {
      short8 a = *(const short8*)&AbufA[colL][kt * 32 + q * 8];
#pragma unroll
      for (int ci = 0; ci < 2; ++ci)
        accH[ci] = __builtin_amdgcn_mfma_f32_16x16x32_bf16(a, w1f[ci][kt], accH[ci], 0, 0, 0);
    }
#pragma unroll
    for (int e = 0; e < 8; ++e)
      AbufB[q * 4 + (e & 3)][(ctBase + (e >> 2)) * 16 + colL] =
          f2bf(fast_tanh(accH[e >> 2][e & 3]));
    __syncthreads();
    f32x4 accF[2];
#pragma unroll
    for (int ci = 0; ci < 2; ++ci) accF[ci] = f32x4{b2c[ci], b2c[ci], b2c[ci], b2c[ci]};
#pragma unroll
    for (int kt = 0; kt < 4; ++kt) {
      short8 a = *(const short8*)&AbufB[colL][kt * 32 + q * 8];
#pragma unroll
      for (int ci = 0; ci < 2; ++ci)
        accF[ci] = __builtin_amdgcn_mfma_f32_16x16x32_bf16(a, w2f[ci][kt], accF[ci], 0, 0, 0);
    }
#pragma unroll
    for (int e = 0; e < 8; ++e) kout[e] = accF[e >> 2][e & 3];
  };

  // ---------- main fixed-step Dopri5 loop ----------
  const float T = tptr[0] / 10.0f;  // t[0] / TIMESCALE
  float tt = 0.f;
  float k1[8], k2[8], k3[8], k4[8], k5[8], k6[8], yv[8];

#pragma unroll 1
  for (int it = 0; it < 48; ++it) {
    float dt = fminf(fmaxf(T - tt, 0.f), dt0v);
    if (dt > 0.f) {  // uniform across all threads and blocks
      stage(yr); evalF(k1);
#pragma unroll
      for (int e = 0; e < 8; ++e) yv[e] = yr[e] + dt * (0.2f * k1[e]);
      stage(yv); evalF(k2);
#pragma unroll
      for (int e = 0; e < 8; ++e) yv[e] = yr[e] + dt * (0.075f * k1[e] + 0.225f * k2[e]);
      stage(yv); evalF(k3);
#pragma unroll
      for (int e = 0; e < 8; ++e)
        yv[e] = yr[e] + dt * (0.9777777777777777f * k1[e] - 3.7333333333333334f * k2[e]
                            + 3.5555555555555554f * k3[e]);
      stage(yv); evalF(k4);
#pragma unroll
      for (int e = 0; e < 8; ++e)
        yv[e] = yr[e] + dt * (2.9525986892242035f * k1[e] - 11.595793324188385f * k2[e]
                            + 9.822892851699436f * k3[e] - 0.2908093278463649f * k4[e]);
      stage(yv); evalF(k5);
#pragma unroll
      for (int e = 0; e < 8; ++e)
        yv[e] = yr[e] + dt * (2.8462752525252526f * k1[e] - 10.757575757575758f * k2[e]
                            + 8.906422717743473f * k3[e] + 0.2784090909090909f * k4[e]
                            - 0.27351165254237287f * k5[e]);
      stage(yv); evalF(k6);
#pragma unroll
      for (int e = 0; e < 8; ++e)
        yr[e] += dt * (0.0911458333333333f * k1[e] + 0.449236298292902f * k3[e]
                     + 0.6510416666666666f * k4[e] - 0.32237617924528303f * k5[e]
                     + 0.13095238095238096f * k6[e]);
    }
    tt += dt;
  }

  // ---------- epilogue: out = stack([x, yT]) ----------
  {
    const float4* x4 = (const float4*)(x + blockRow * 128);
    float4* o4 = (float4*)(out + blockRow * 128);
#pragma unroll 1
    for (int i = tid; i < 512; i += 256) o4[i] = x4[i];
    float* oy = out + 8192 * 128;
#pragma unroll
    for (int e = 0; e < 8; ++e)
      oy[(blockRow + q * 4 + (e & 3)) * 128 + (ctBase + (e >> 2)) * 16 + colL] = yr[e];
  }
}

extern "C" void kernel_launch(void* const* d_in, const int* in_sizes, int n_in,
                              void* d_out, int out_size, void* d_ws, size_t ws_size,
                              hipStream_t stream) {
  const float* t  = (const float*)d_in[0];
  const float* x  = (const float*)d_in[1];
  const float* W1 = (const float*)d_in[2];
  const float* b1 = (const float*)d_in[3];
  const float* W2 = (const float*)d_in[4];
  const float* b2 = (const float*)d_in[5];
  float* out = (float*)d_out;
  node_kernel<<<dim3(512), dim3(256), 0, stream>>>(t, x, W1, b1, W2, b2, out);
}

// Round 3
// 168.300 us; speedup vs baseline: 1.2804x; 1.0224x over previous
//
#include <hip/hip_runtime.h>

// NeuralODE: y' = tanh(y@W1+b1)@W2+b2, fixed-step Dopri5, 48 static iters.
// R3: block = 512 threads x 16 rows; each wave owns ONE 16-col tile (8 tiles =
// 8 waves). 512 blocks -> 16 waves/CU (4 waves/SIMD) for latency hiding.
// Weights as B-frags in registers (32 VGPR/wave), state f32x4 in C/D layout
// (col=lane&15, row=quad*4+reg). dt0 recomputed per block (fp32, split-K).

typedef __attribute__((ext_vector_type(8))) short short8;  // 8 bf16 = 4 VGPRs
typedef __attribute__((ext_vector_type(4))) float f32x4;

#define SL 136  // LDS row stride in bf16: 272B = 16B-aligned rows (b128 reads)

__device__ __forceinline__ short f2bf(float f) {
  union { float f; unsigned u; } v; v.f = f;
  return (short)((v.u + 0x8000u) >> 16);  // round-half-up, plenty for 0.1 budget
}

__device__ __forceinline__ float fast_tanh(float x) {
  // tanh(x) = 1 - 2/(e^{2x}+1); exact at +-inf, no branches.
  float e = __expf(2.0f * x);
  return 1.0f - __fdividef(2.0f, e + 1.0f);
}

__global__ __launch_bounds__(512, 4)
void node_kernel(const float* __restrict__ tptr, const float* __restrict__ x,
                 const float* __restrict__ W1, const float* __restrict__ b1,
                 const float* __restrict__ W2, const float* __restrict__ b2,
                 float* __restrict__ out) {
  const int tid  = threadIdx.x;
  const int lane = tid & 63;
  const int ct   = tid >> 6;      // wave id == col-tile id (0..7)
  const int q    = lane >> 4;     // quad within wave
  const int colL = lane & 15;     // col within tile (C layout) / m row (A frag)
  const int n    = ct * 16 + colL;  // global col this thread owns
  const int blockRow = blockIdx.x * 16;

  __shared__ short A1[16][SL];   // staged y' (bf16, A-operand layout)
  __shared__ short A2[16][SL];   // staged tanh hidden (bf16)
  __shared__ float sred[512];
  __shared__ float spart[4][128];
  __shared__ float srowY[128], srowH[128], srowF[128], srowY2[128], srowF2[128], sscale[128];

  // ---------- weight B-fragments (bf16) + biases into registers ----------
  // B-frag 16x16x32: lane holds B[k = quad*8 + j][n = lane&15], j=0..7.
  short8 w1f[4], w2f[4];
  const float b1c = b1[n], b2c = b2[n];
#pragma unroll
  for (int kt = 0; kt < 4; ++kt) {
    short8 v1, v2;
#pragma unroll
    for (int j = 0; j < 8; ++j) {
      const int k = kt * 32 + q * 8 + j;
      v1[j] = f2bf(W1[k * 128 + n]);
      v2[j] = f2bf(W2[k * 128 + n]);
    }
    w1f[kt] = v1; w2f[kt] = v2;
  }

  // ---------- block-wide sum (512 threads) ----------
  auto block_sum = [&](float v) -> float {
    sred[tid] = v;
    __syncthreads();
    if (tid < 64) {
      float s = 0.f;
#pragma unroll
      for (int i = 0; i < 8; ++i) s += sred[tid + 64 * i];
#pragma unroll
      for (int o = 32; o > 0; o >>= 1) s += __shfl_down(s, o, 64);
      if (tid == 0) sred[0] = s;
    }
    __syncthreads();
    float r = sred[0];
    __syncthreads();
    return r;
  };

  // ---------- one MLP layer for a single row (fp32, split-K over 512 thr) ----------
  auto mlp_layer = [&](const float* vin, const float* Wg, const float* bg,
                       float* vout, bool dotanh) {
    const int col = tid & 127, part = tid >> 7;  // 4 K-chunks of 32
    float s = 0.f;
    const float* wp = Wg + (part * 32) * 128 + col;
#pragma unroll 8
    for (int j = 0; j < 32; ++j) s += vin[part * 32 + j] * wp[j * 128];
    spart[part][col] = s;
    __syncthreads();
    if (tid < 128) {
      float a = bg[tid] + spart[0][tid] + spart[1][tid] + spart[2][tid] + spart[3][tid];
      vout[tid] = dotanh ? fast_tanh(a) : a;
    }
    __syncthreads();
  };

  // ---------- dt0: faithful port of initial_step_size (row 0, fp32) ----------
  if (tid < 128) srowY[tid] = x[tid];
  __syncthreads();
  mlp_layer(srowY, W1, b1, srowH, true);
  mlp_layer(srowH, W2, b2, srowF, false);
  float t0 = 0.f, t1 = 0.f;
  if (tid < 128) {
    float sc = 1.4e-8f + fabsf(srowY[tid]) * 1.4e-8f;
    sscale[tid] = sc;
    float a = srowY[tid] / sc; t0 = a * a;
    float bq = srowF[tid] / sc; t1 = bq * bq;
  }
  float d0 = sqrtf(block_sum(t0));
  float d1 = sqrtf(block_sum(t1));
  float h0 = (d0 < 1e-5f || d1 < 1e-5f) ? 1e-6f : 0.01f * d0 / d1;
  if (tid < 128) srowY2[tid] = srowY[tid] + h0 * srowF[tid];
  __syncthreads();
  mlp_layer(srowY2, W1, b1, srowH, true);
  mlp_layer(srowH, W2, b2, srowF2, false);
  float t2 = 0.f;
  if (tid < 128) { float a = (srowF2[tid] - srowF[tid]) / sscale[tid]; t2 = a * a; }
  float d2 = sqrtf(block_sum(t2)) / h0;
  float h1 = (d1 <= 1e-15f && d2 <= 1e-15f) ? fmaxf(1e-6f, h0 * 1e-3f)
                                            : powf(0.01f / (d1 + d2), 0.2f);
  const float dt0v = fminf(100.f * h0, h1);

  // ---------- load state y (C-layout ownership: 4 elems/thread) ----------
  f32x4 yr;
#pragma unroll
  for (int r = 0; r < 4; ++r) yr[r] = x[(blockRow + q * 4 + r) * 128 + n];

  // hoisted LDS addresses (constant immediate offsets thereafter)
  short* wr1 = &A1[q * 4][n];
  short* wr2 = &A2[q * 4][n];
  const short* rd1 = &A1[colL][q * 8];
  const short* rd2 = &A2[colL][q * 8];

  // ---------- one f-eval: LDS round-trip transpose + 2 MFMA layers ----------
  auto evalF = [&](f32x4 yin) -> f32x4 {
#pragma unroll
    for (int r = 0; r < 4; ++r) wr1[r * SL] = f2bf(yin[r]);
    __syncthreads();
    f32x4 acc = {b1c, b1c, b1c, b1c};
#pragma unroll
    for (int kt = 0; kt < 4; ++kt)
      acc = __builtin_amdgcn_mfma_f32_16x16x32_bf16(
          *(const short8*)(rd1 + kt * 32), w1f[kt], acc, 0, 0, 0);
#pragma unroll
    for (int r = 0; r < 4; ++r) wr2[r * SL] = f2bf(fast_tanh(acc[r]));
    __syncthreads();
    f32x4 accF = {b2c, b2c, b2c, b2c};
#pragma unroll
    for (int kt = 0; kt < 4; ++kt)
      accF = __builtin_amdgcn_mfma_f32_16x16x32_bf16(
          *(const short8*)(rd2 + kt * 32), w2f[kt], accF, 0, 0, 0);
    return accF;
  };

  // ---------- main fixed-step Dopri5 loop ----------
  const float T = tptr[0] / 10.0f;  // t[0] / TIMESCALE
  float tt = 0.f;

#pragma unroll 1
  for (int it = 0; it < 48; ++it) {
    float dt = fminf(fmaxf(T - tt, 0.f), dt0v);
    if (dt > 0.f) {  // uniform across threads and blocks
      f32x4 k1 = evalF(yr);
      f32x4 k2 = evalF(yr + dt * (0.2f * k1));
      f32x4 k3 = evalF(yr + dt * (0.075f * k1 + 0.225f * k2));
      f32x4 k4 = evalF(yr + dt * (0.9777777777777777f * k1 - 3.7333333333333334f * k2
                                + 3.5555555555555554f * k3));
      f32x4 k5 = evalF(yr + dt * (2.9525986892242035f * k1 - 11.595793324188385f * k2
                                + 9.822892851699436f * k3 - 0.2908093278463649f * k4));
      f32x4 k6 = evalF(yr + dt * (2.8462752525252526f * k1 - 10.757575757575758f * k2
                                + 8.906422717743473f * k3 + 0.2784090909090909f * k4
                                - 0.27351165254237287f * k5));
      yr = yr + dt * (0.0911458333333333f * k1 + 0.449236298292902f * k3
                    + 0.6510416666666666f * k4 - 0.32237617924528303f * k5
                    + 0.13095238095238096f * k6);
    }
    tt += dt;
  }

  // ---------- epilogue: out = stack([x, yT]) ----------
  {
    const float4* x4 = (const float4*)(x + blockRow * 128);
    float4* o4 = (float4*)(out + blockRow * 128);
    o4[tid] = x4[tid];  // 16 rows * 128 f32 = 512 float4
    float* oy = out + 8192 * 128;
#pragma unroll
    for (int r = 0; r < 4; ++r)
      oy[(blockRow + q * 4 + r) * 128 + n] = yr[r];
  }
}

extern "C" void kernel_launch(void* const* d_in, const int* in_sizes, int n_in,
                              void* d_out, int out_size, void* d_ws, size_t ws_size,
                              hipStream_t stream) {
  const float* t  = (const float*)d_in[0];
  const float* x  = (const float*)d_in[1];
  const float* W1 = (const float*)d_in[2];
  const float* b1 = (const float*)d_in[3];
  const float* W2 = (const float*)d_in[4];
  const float* b2 = (const float*)d_in[5];
  float* out = (float*)d_out;
  node_kernel<<<dim3(512), dim3(512), 0, stream>>>(t, x, W1, b1, W2, b2, out);
}